// Round 5
// baseline (88.224 us; speedup 1.0000x reference)
//
#include <hip/hip_runtime.h>
#include <hip/hip_bf16.h>

typedef __attribute__((ext_vector_type(8))) short bf16x8;
typedef __attribute__((ext_vector_type(4))) short s16x4;
typedef __attribute__((ext_vector_type(4))) float f32x4;

#define B_ 64
#define T_ 1024
#define N_ 512

__device__ __forceinline__ short f2bf(float f) {
  return __builtin_bit_cast(short, __float2bfloat16(f));
}
__device__ __forceinline__ float bf2f(short s) {
  return __builtin_bit_cast(float, ((unsigned)(unsigned short)s) << 16);
}

// 32 k-rows x 128 n-cols fp32, reg-staged. thread: n-chunk=(tid&31)*4 (float4),
// k-quad=(tid>>5)*4. v[r] = k-row +r, cols n..n+3.
struct Slab { float4 v[4]; };

__device__ __forceinline__ void slab_load(const float* __restrict__ Xb, int kb,
                                          int pbase, int tid, Slab& s) {
  const int n = (tid & 31) * 4, k = (tid >> 5) * 4;
  const float* base = Xb + (size_t)(kb + k) * N_ + pbase + n;
  #pragma unroll
  for (int r = 0; r < 4; ++r)
    s.v[r] = *(const float4*)(base + (size_t)r * N_);
}

// LDS elem layout: row*32 + chunk*8 + sub; chunk XOR-swizzle cg^((row>>1)&3)
// (same involution as the fragment read -> rule #21 satisfied). Also
// accumulates per-column sum/sumsq of the bf16-ROUNDED values (MFMA-consistent).
__device__ __forceinline__ void slab_write(short* lds, int tid, const Slab& s,
                                           float (&st)[4], float (&qt)[4]) {
  const int nq = tid & 31, kq = tid >> 5;
  const int cg = kq >> 1, h = kq & 1;
  const float* f = (const float*)&s.v[0];          // f[r*4 + c]
  #pragma unroll
  for (int c = 0; c < 4; ++c) {
    const int row = nq * 4 + c;
    const int cc = cg ^ ((row >> 1) & 3);
    s16x4 pk;
    #pragma unroll
    for (int r = 0; r < 4; ++r) {
      pk[r] = f2bf(f[r * 4 + c]);
      const float fv = bf2f(pk[r]);
      st[c] += fv; qt[c] += fv * fv;
    }
    *(s16x4*)&lds[row * 32 + cc * 8 + h * 4] = pk;  // transpose = reg renaming
  }
}

__device__ __forceinline__ void compute_step(
    const short* A, const short* Bm, int aoff, int boff, int swz,
    f32x4 (&acc)[4][4])
{
  bf16x8 af[4], bfv[4];
  #pragma unroll
  for (int mi = 0; mi < 4; ++mi) af[mi] = *(const bf16x8*)&A[aoff + mi*512 + swz];
  #pragma unroll
  for (int ni = 0; ni < 4; ++ni) bfv[ni] = *(const bf16x8*)&Bm[boff + ni*512 + swz];
  #pragma unroll
  for (int mi = 0; mi < 4; ++mi)
    #pragma unroll
    for (int ni = 0; ni < 4; ++ni)
      acc[mi][ni] = __builtin_amdgcn_mfma_f32_16x16x32_bf16(
          af[mi], bfv[ni], acc[mi][ni], 0, 0, 0);
}

// One block per upper-tri 128x128 tile (10/batch x 64 batches = 640 blocks).
// Reads raw fp32 X, converts+transposes in-register, computes stats inline.
__global__ __launch_bounds__(256, 3) void k_fused(
    const float* __restrict__ X, float* __restrict__ out)
{
  __shared__ __align__(16) short lds[2][2][4096];   // [buf][A/B] 32 KB
  __shared__ float sMu[256], sId[256];              // A:0-127, B:128-255

  const int bid = (blockIdx.x & 7) * 80 + (blockIdx.x >> 3);  // 640 = 8 XCD x 80
  const int b = bid / 10;
  const int t = bid - b * 10;
  const int ip = (t >= 4) + (t >= 7) + (t >= 9);
  const int jp = ip + t - ((ip * (9 - ip)) >> 1);
  const int rowBase = ip * 128, colBase = jp * 128;
  const bool diag = (ip == jp);

  const int tid = threadIdx.x, lane = tid & 63, wave = tid >> 6;
  const int wr = wave >> 1, wc = wave & 1;
  const int fr = lane & 15, kc = lane >> 4;
  const int swz  = (kc ^ ((fr >> 1) & 3)) * 8;
  const int aoff = (wr * 64 + fr) * 32;
  const int boff = (wc * 64 + fr) * 32;
  const float* Xb = X + (size_t)b * T_ * N_;

  float sA[4] = {0,0,0,0}, qA[4] = {0,0,0,0};
  float sB[4] = {0,0,0,0}, qB[4] = {0,0,0,0};
  f32x4 acc[4][4] = {};

  Slab a, bb;
  slab_load(Xb, 0, rowBase, tid, a);
  if (!diag) slab_load(Xb, 0, colBase, tid, bb);
  slab_write(lds[0][0], tid, a, sA, qA);
  if (!diag) slab_write(lds[0][1], tid, bb, sB, qB);
  __syncthreads();

  int cur = 0;
  #pragma unroll 1
  for (int kt = 0; kt < 32; ++kt) {
    if (kt < 31) {                                   // issue loads early (T14)
      slab_load(Xb, (kt + 1) * 32, rowBase, tid, a);
      if (!diag) slab_load(Xb, (kt + 1) * 32, colBase, tid, bb);
    }
    compute_step(lds[cur][0], diag ? lds[cur][0] : lds[cur][1],
                 aoff, boff, swz, acc);
    if (kt < 31) {                                   // write after compute
      slab_write(lds[cur ^ 1][0], tid, a, sA, qA);
      if (!diag) slab_write(lds[cur ^ 1][1], tid, bb, sB, qB);
    }
    __syncthreads();
    cur ^= 1;
  }

  // ---- stats block-reduce (staging LDS reused as fp32 scratch) ----
  float* fb = (float*)&lds[0][0][0];                 // 8192 floats = 32 KB
  const int nq = tid & 31, kq = tid >> 5;
  #pragma unroll
  for (int c = 0; c < 4; ++c) {
    const int col = nq * 4 + c;
    fb[       col * 8 + kq] = sA[c];
    fb[1024 + col * 8 + kq] = qA[c];
    fb[2048 + col * 8 + kq] = sB[c];
    fb[3072 + col * 8 + kq] = qB[c];
  }
  __syncthreads();
  {
    const int base = (tid < 128) ? 0 : 2048;
    const int col  = tid & 127;
    float rs = 0.f, ss = 0.f;
    #pragma unroll
    for (int k = 0; k < 8; ++k) {
      rs += fb[base +        col * 8 + k];
      ss += fb[base + 1024 + col * 8 + k];
    }
    sMu[tid] = rs * (1.f / 32.f);                    // rs / sqrt(T)
    sId[tid] = rsqrtf(fmaxf(ss - rs * rs * (1.f / 1024.f), 1e-20f));
  }
  __syncthreads();

  // ---- epilogue. C/D map: col = lane&15, row = (lane>>4)*4 + reg ----
  const int jb = diag ? 0 : 128;
  const int jl = wc * 64 + fr;
  float aj[4], dj[4];
  #pragma unroll
  for (int ni = 0; ni < 4; ++ni) {
    aj[ni] = sMu[jb + jl + ni * 16];
    dj[ni] = sId[jb + jl + ni * 16];
  }
  #pragma unroll
  for (int mi = 0; mi < 4; ++mi) {
    const int il = wr * 64 + mi * 16 + kc * 4;
    float ai[4], di[4];
    #pragma unroll
    for (int r = 0; r < 4; ++r) { ai[r] = sMu[il + r]; di[r] = sId[il + r]; }
    #pragma unroll
    for (int ni = 0; ni < 4; ++ni) {
      f32x4 g;
      #pragma unroll
      for (int r = 0; r < 4; ++r) {
        float v = (acc[mi][ni][r] - ai[r] * aj[ni]) * (di[r] * dj[ni]);
        g[r] = fminf(fmaxf(v, -1.f), 1.f);
      }
      const int J = colBase + jl + ni * 16;
      #pragma unroll
      for (int r = 0; r < 4; ++r)
        out[((size_t)b * N_ + rowBase + il + r) * N_ + J] = g[r];   // tile
      if (!diag)
        *(f32x4*)&out[((size_t)b * N_ + J) * N_ + rowBase + il] = g; // mirror
    }
  }
}

extern "C" void kernel_launch(void* const* d_in, const int* in_sizes, int n_in,
                              void* d_out, int out_size, void* d_ws, size_t ws_size,
                              hipStream_t stream) {
  const float* X = (const float*)d_in[0];
  // bn_weight / bn_bias provably cancel in the correlation output.
  float* out = (float*)d_out;
  k_fused<<<dim3(640), 256, 0, stream>>>(X, out);
}